// Round 1
// baseline (194.304 us; speedup 1.0000x reference)
//
#include <hip/hip_runtime.h>
#include <hip/hip_bf16.h>

#define OMEGA0 30.0f
#define IN_DIM 512
#define OUT_DIM 512
#define BM 128
#define BN 128
#define BK 64

typedef _Float16 f16;
typedef __attribute__((ext_vector_type(8))) _Float16 f16x8;
typedef __attribute__((ext_vector_type(4))) float f32x4;

// ---------------- pre-kernel 1: theta16[o][k] = f16(30*theta[o][k]) ----------------
__global__ void cvt_theta_kernel(const float* __restrict__ theta, f16* __restrict__ theta16) {
    int idx = (blockIdx.x * 256 + threadIdx.x) * 8;
    f32x4 a = *(const f32x4*)(theta + idx);
    f32x4 b = *(const f32x4*)(theta + idx + 4);
    f16x8 o;
#pragma unroll
    for (int i = 0; i < 4; i++) { o[i] = (f16)(OMEGA0 * a[i]); o[4 + i] = (f16)(OMEGA0 * b[i]); }
    *(f16x8*)(theta16 + idx) = o;
}

// ---------------- pre-kernel 2: bias[o] = 30*sum_k theta[o][k] + phi[o] ----------------
__global__ void make_bias_kernel(const float* __restrict__ theta, const float* __restrict__ phi,
                                 float* __restrict__ bias) {
    int w = threadIdx.x >> 6, lane = threadIdx.x & 63;
    int o = blockIdx.x * 4 + w;
    const float* row = theta + (long)o * IN_DIM + lane * 8;
    f32x4 a = *(const f32x4*)row;
    f32x4 b = *(const f32x4*)(row + 4);
    float s = a[0] + a[1] + a[2] + a[3] + b[0] + b[1] + b[2] + b[3];
#pragma unroll
    for (int off = 32; off; off >>= 1) s += __shfl_down(s, off, 64);
    if (lane == 0) bias[o] = OMEGA0 * s + phi[o];
}

// ---------------- main GEMM + cos epilogue ----------------
// C[m][o] = cos( sum_k x[m][k] * theta30[o][k] + bias[o] )
// 128x128 tile, BK=64, 4 waves (2x2), 16x16x32 f16 MFMA, double-buffered LDS.
// B staged via global_load_lds (fp16, pre-converted). A reg-staged fp32->f16 (T14 split).
__launch_bounds__(256, 2)
__global__ void siren_gemm_kernel(const float* __restrict__ x, const f16* __restrict__ theta16,
                                  const float* __restrict__ bias, float* __restrict__ out) {
    __shared__ f16 ldsA[2][BM * BK];
    __shared__ f16 ldsB[2][BM * BK];

    // XCD-chunked swizzle (grid = 4096, divisible by 8): consecutive swz share A-panel
    int nwg = gridDim.x;
    int bid = blockIdx.x;
    int cpx = nwg >> 3;
    int swz = (bid & 7) * cpx + (bid >> 3);
    int mt = swz >> 2;          // 1024 m-tiles
    int nt = swz & 3;           // 4 n-tiles
    long m0 = (long)mt * BM;
    int n0 = nt * BN;

    int t = threadIdx.x;
    int w = t >> 6, lane = t & 63;
    int wm = w >> 1, wn = w & 1;          // 2x2 wave grid, wave tile 64x64

    f32x4 acc[4][4] = {};                 // 4x4 fragments of 16x16
    f32x4 ar[4][2];                       // A-stage registers (8 fp32 per pass, 4 passes)

    int sr = t >> 3;                      // staging row within 32-row pass
    int sc = (t & 7) * 8;                 // staging col (8 elems)

    // ---- staging helpers ----
    auto A_ISSUE = [&](int kt) {
        const float* src = x + m0 * IN_DIM + kt * BK + sc;
#pragma unroll
        for (int p = 0; p < 4; p++) {
            const float* pr = src + (long)(sr + p * 32) * IN_DIM;
            ar[p][0] = *(const f32x4*)pr;
            ar[p][1] = *(const f32x4*)(pr + 4);
        }
    };
    auto A_WRITE = [&](int buf) {
#pragma unroll
        for (int p = 0; p < 4; p++) {
            f16x8 v;
#pragma unroll
            for (int i = 0; i < 4; i++) { v[i] = (f16)ar[p][0][i]; v[4 + i] = (f16)ar[p][1][i]; }
            *(f16x8*)(&ldsA[buf][(sr + p * 32) * BK + sc]) = v;
        }
    };
    auto B_STAGE = [&](int kt, int buf) {
        const f16* src = theta16 + (long)n0 * IN_DIM + kt * BK;
#pragma unroll
        for (int j = 0; j < 4; j++) {
            int row = j * 32 + w * 8 + (lane >> 3);
            int col = (lane & 7) * 8;
            __builtin_amdgcn_global_load_lds(
                (const __attribute__((address_space(1))) char*)(const char*)(src + (long)row * IN_DIM + col),
                (__attribute__((address_space(3))) char*)(char*)(&ldsB[buf][row * BK + col]),
                16, 0, 0);
        }
    };

    int lr = lane & 15, lk = lane >> 4;   // fragment lane decode

    auto COMPUTE = [&](int buf) {
        f16x8 afrag[4][2], bfrag[4][2];
        const f16* A = &ldsA[buf][0];
        const f16* Bp = &ldsB[buf][0];
#pragma unroll
        for (int fm = 0; fm < 4; fm++)
#pragma unroll
            for (int kh = 0; kh < 2; kh++)
                afrag[fm][kh] = *(const f16x8*)&A[(wm * 64 + fm * 16 + lr) * BK + kh * 32 + lk * 8];
#pragma unroll
        for (int fn = 0; fn < 4; fn++)
#pragma unroll
            for (int kh = 0; kh < 2; kh++)
                bfrag[fn][kh] = *(const f16x8*)&Bp[(wn * 64 + fn * 16 + lr) * BK + kh * 32 + lk * 8];
#pragma unroll
        for (int fm = 0; fm < 4; fm++)
#pragma unroll
            for (int fn = 0; fn < 4; fn++)
#pragma unroll
                for (int kh = 0; kh < 2; kh++)
                    acc[fm][fn] = __builtin_amdgcn_mfma_f32_16x16x32_f16(
                        afrag[fm][kh], bfrag[fn][kh], acc[fm][fn], 0, 0, 0);
    };

    // ---- prologue: stage tile 0 ----
    B_STAGE(0, 0);
    A_ISSUE(0);
    A_WRITE(0);

    // ---- main loop: 8 K-steps, double-buffered ----
#pragma unroll 1
    for (int kt = 0; kt < IN_DIM / BK; kt++) {
        int cur = kt & 1;
        __syncthreads();                       // staged data for buf[cur] visible
        if (kt < IN_DIM / BK - 1) {
            B_STAGE(kt + 1, cur ^ 1);          // async into other buffer
            A_ISSUE(kt + 1);                   // issue global loads early (T14)
        }
        COMPUTE(cur);
        if (kt < IN_DIM / BK - 1) {
            A_WRITE(cur ^ 1);                  // cvt + ds_write after MFMA hides latency
        }
    }

    // ---- epilogue: cos(acc + bias[col]) ----
    int lq = lane >> 4;
#pragma unroll
    for (int fn = 0; fn < 4; fn++) {
        int col = n0 + wn * 64 + fn * 16 + lr;
        float bv = bias[col];
#pragma unroll
        for (int fm = 0; fm < 4; fm++) {
            long row0 = m0 + wm * 64 + fm * 16 + lq * 4;
#pragma unroll
            for (int r = 0; r < 4; r++) {
                out[(row0 + r) * OUT_DIM + col] = __cosf(acc[fm][fn][r] + bv);
            }
        }
    }
}

extern "C" void kernel_launch(void* const* d_in, const int* in_sizes, int n_in,
                              void* d_out, int out_size, void* d_ws, size_t ws_size,
                              hipStream_t stream) {
    const float* x     = (const float*)d_in[0];
    const float* theta = (const float*)d_in[1];
    const float* phi   = (const float*)d_in[2];
    float* out = (float*)d_out;

    size_t theta16_bytes = (size_t)OUT_DIM * IN_DIM * sizeof(f16);  // 512 KB
    size_t need = theta16_bytes + OUT_DIM * sizeof(float);          // + 2 KB bias
    if (ws_size < need) return;  // fail loudly in validation rather than corrupt

    f16*   theta16 = (f16*)d_ws;
    float* bias    = (float*)((char*)d_ws + theta16_bytes);

    int Brows = in_sizes[0] / IN_DIM;  // 131072

    // pre-kernels: convert theta to f16*30, compute bias
    cvt_theta_kernel<<<(OUT_DIM * IN_DIM / 8 + 255) / 256, 256, 0, stream>>>(theta, theta16);
    make_bias_kernel<<<OUT_DIM / 4, 256, 0, stream>>>(theta, phi, bias);

    int grid = (Brows / BM) * (OUT_DIM / BN);  // 1024 * 4 = 4096
    siren_gemm_kernel<<<grid, 256, 0, stream>>>(x, theta16, bias, out);
}